// Round 19
// baseline (238.101 us; speedup 1.0000x reference)
//
#include <hip/hip_runtime.h>
#include <cstdint>

#define DEVI __device__ __forceinline__

typedef float f32x4 __attribute__((ext_vector_type(4)));
typedef __bf16 bf16x8 __attribute__((ext_vector_type(8)));
typedef unsigned int u32x4v __attribute__((ext_vector_type(4)));
typedef unsigned short u16;
typedef unsigned int u32;
typedef unsigned long long u64;

#define LOG2E 1.44269504088896f
#define QSCALE (0.125f * LOG2E)

// ---------- helpers ----------
DEVI u16 bf16bits(float f) {
    u32 u = __builtin_bit_cast(u32, f);
    u32 r = u + 0x7fffu + ((u >> 16) & 1u);
    return (u16)(r >> 16);
}

DEVI float bf2f(u16 v) {
    u32 u = (u32)v << 16;
    return __builtin_bit_cast(float, u);
}

DEVI u32 pack2bf(float a, float b) {
    u16 x = __builtin_bit_cast(u16, (__bf16)a);
    u16 y = __builtin_bit_cast(u16, (__bf16)b);
    return (u32)x | ((u32)y << 16);
}

DEVI float ex2(float x) {
    float r;
    asm("v_exp_f32 %0, %1" : "=v"(r) : "v"(x));
    return r;
}

DEVI void gload16(const void* g, const void* l) {
    __builtin_amdgcn_global_load_lds(
        (const __attribute__((address_space(1))) void*)(u64)(uintptr_t)g,
        (__attribute__((address_space(3))) void*)(u32)(uintptr_t)l,
        16, 0, 0);
}

#define VMCNT0_BARRIER()                                   \
    asm volatile("s_waitcnt vmcnt(0)" ::: "memory");       \
    __builtin_amdgcn_s_barrier()

// ---------- fused prep (vectorized transpose writes) ----------
__global__ __launch_bounds__(256)
void prep_kernel(const float* __restrict__ x, u16* __restrict__ xb,
                 const float* __restrict__ Wq, const float* __restrict__ Wk,
                 const float* __restrict__ Wv, const float* __restrict__ Wo,
                 u16* __restrict__ Wqt, u16* __restrict__ Wkt,
                 u16* __restrict__ Wvt, u16* __restrict__ Wot,
                 const float* __restrict__ W1, u16* __restrict__ W1t,
                 const float* __restrict__ W2, u16* __restrict__ W2t) {
    __shared__ float t[64][65];
    const int b = blockIdx.x;
    const int tid = threadIdx.x;
    if (b < 4096) {
        int i = b * 256 + tid;
        float4 v = ((const float4*)x)[i];
        ((uint2*)xb)[i] = make_uint2(pack2bf(v.x, v.y), pack2bf(v.z, v.w));
        return;
    }
    const float* src;
    u16* dst;
    int K_, N_, k0, n0;
    if (b < 5120) {
        int l = b - 4096;
        int z = l >> 8;
        l &= 255;
        src = z == 0 ? Wq : z == 1 ? Wk : z == 2 ? Wv : Wo;
        dst = z == 0 ? Wqt : z == 1 ? Wkt : z == 2 ? Wvt : Wot;
        K_ = 1024; N_ = 1024;
        k0 = (l & 15) * 64; n0 = (l >> 4) * 64;
    } else if (b < 6144) {
        int l = b - 5120;
        src = W1; dst = W1t; K_ = 1024; N_ = 4096;
        k0 = (l & 15) * 64; n0 = (l >> 4) * 64;
    } else {
        int l = b - 6144;
        src = W2; dst = W2t; K_ = 4096; N_ = 1024;
        k0 = (l & 63) * 64; n0 = (l >> 6) * 64;
    }
#pragma unroll
    for (int i = 0; i < 16; i++) {
        int idx = i * 256 + tid;
        int r = idx >> 6, c = idx & 63;
        t[r][c] = src[(u64)(k0 + r) * N_ + n0 + c];
    }
    __syncthreads();
#pragma unroll
    for (int i = 0; i < 4; i++) {
        int idx = i * 256 + tid;
        int cq = idx & 15;
        int r = idx >> 4;
        u32 lo = (u32)bf16bits(t[cq * 4 + 0][r]) | ((u32)bf16bits(t[cq * 4 + 1][r]) << 16);
        u32 hi = (u32)bf16bits(t[cq * 4 + 2][r]) | ((u32)bf16bits(t[cq * 4 + 3][r]) << 16);
        *(uint2*)(dst + (u64)(n0 + r) * K_ + k0 + cq * 4) = make_uint2(lo, hi);
    }
}

// ---------- GEMM A: 128x128 tile, 512 threads / 8 waves ----------
enum { MODE_QK = 0, MODE_VT = 1, MODE_RELU = 3 };

DEVI void gemm_core(const u16* __restrict__ A, const u16* __restrict__ Bt, int K_,
                    u16 (*ldsA)[128 * 64], u16 (*ldsB)[128 * 64],
                    f32x4 (&acc)[2][4], int m0, int n0) {
    const int tid = threadIdx.x;
    const int lane = tid & 63;
    const int w = tid >> 6;
    const int wr = w >> 1, wc = w & 1;
    const int l15 = lane & 15, l4 = lane >> 4;
    const int srow = tid >> 3;
    const int sc = (tid & 7) ^ (srow & 7);

    const u16* ap[2];
    const u16* bp[2];
    ap[0] = A + (u64)(m0 + srow) * K_ + sc * 8;
    ap[1] = A + (u64)(m0 + 64 + srow) * K_ + sc * 8;
    bp[0] = Bt + (u64)(n0 + srow) * K_ + sc * 8;
    bp[1] = Bt + (u64)(n0 + 64 + srow) * K_ + sc * 8;

    auto stage = [&](int buf) {
#pragma unroll
        for (int i = 0; i < 2; i++) {
            gload16(ap[i], (const char*)ldsA[buf] + (i * 512 + tid) * 16);
            ap[i] += 64;
        }
#pragma unroll
        for (int i = 0; i < 2; i++) {
            gload16(bp[i], (const char*)ldsB[buf] + (i * 512 + tid) * 16);
            bp[i] += 64;
        }
    };

    auto compute = [&](const u16* A_, const u16* B_) {
#pragma unroll
        for (int ks = 0; ks < 2; ks++) {
            bf16x8 af[2], bfr[4];
#pragma unroll
            for (int mi = 0; mi < 2; mi++) {
                int row = wr * 32 + mi * 16 + l15;
                af[mi] = *(const bf16x8*)((const char*)A_ + row * 128 +
                                          (((ks * 4 + l4) ^ (row & 7)) * 16));
            }
#pragma unroll
            for (int ni = 0; ni < 4; ni++) {
                int row = wc * 64 + ni * 16 + l15;
                bfr[ni] = *(const bf16x8*)((const char*)B_ + row * 128 +
                                           (((ks * 4 + l4) ^ (row & 7)) * 16));
            }
            __builtin_amdgcn_s_setprio(1);
#pragma unroll
            for (int mi = 0; mi < 2; mi++)
#pragma unroll
                for (int ni = 0; ni < 4; ni++)
                    acc[mi][ni] = __builtin_amdgcn_mfma_f32_16x16x32_bf16(
                        af[mi], bfr[ni], acc[mi][ni], 0, 0, 0);
            __builtin_amdgcn_s_setprio(0);
        }
    };

    const int nk = K_ >> 6;
    stage(0);
    VMCNT0_BARRIER();
    for (int t = 0; t < nk; t += 2) {
        if (t + 1 < nk) stage(1);
        compute(ldsA[0], ldsB[0]);
        VMCNT0_BARRIER();
        if (t + 2 < nk) stage(0);
        compute(ldsA[1], ldsB[1]);
        VMCNT0_BARRIER();
    }
}

template <int MODE>
DEVI void gemm_epilogue(f32x4 (&acc)[2][4], const float* __restrict__ bias,
                        void* __restrict__ outp, int N_, int m0, int n0,
                        float scale, u16* l16) {
    const int tid = threadIdx.x;
    const int lane = tid & 63;
    const int w = tid >> 6;
    const int wr = w >> 1, wc = w & 1;
    const int l15 = lane & 15, l4 = lane >> 4;
    __syncthreads();
#pragma unroll
    for (int mi = 0; mi < 2; mi++) {
#pragma unroll
        for (int ni = 0; ni < 4; ni++) {
            const int nl = wc * 64 + ni * 16 + l15;
            const int mlb = wr * 32 + mi * 16 + l4 * 4;
            const float bv = bias[n0 + nl];
            if (MODE == MODE_VT) {
                u32 lo = pack2bf(acc[mi][ni][0] + bv, acc[mi][ni][1] + bv);
                u32 hi = pack2bf(acc[mi][ni][2] + bv, acc[mi][ni][3] + bv);
                *(uint2*)(l16 + nl * 136 + mlb) = make_uint2(lo, hi);
            } else {
#pragma unroll
                for (int r = 0; r < 4; r++) {
                    float v = acc[mi][ni][r] + bv;
                    if (MODE == MODE_RELU) v = fmaxf(v, 0.f);
                    else v = v * scale;
                    l16[(mlb + r) * 136 + nl] = bf16bits(v);
                }
            }
        }
    }
    __syncthreads();
#pragma unroll
    for (int it = 0; it < 4; it++) {
        int c = it * 512 + tid;
        int rr = c >> 4, nc = c & 15;
        u32x4v v = *(const u32x4v*)(l16 + rr * 136 + nc * 8);
        if (MODE == MODE_QK) {
            int m = m0 + rr;
            int b = m >> 11, t = m & 2047;
            int hh = (n0 >> 6) + (nc >> 3);
            int d = (nc & 7) * 8;
            *(u32x4v*)((u16*)outp + (((u64)((b << 4) + hh) * 2048 + t) << 6) + d) = v;
        } else if (MODE == MODE_VT) {
            int hh = (n0 + rr) >> 6;
            int d = (n0 + rr) & 63;
            int b = m0 >> 11, tb = m0 & 2047;
            *(u32x4v*)((u16*)outp + ((u64)((b << 4) + hh) * 64 + d) * 2048 + tb + nc * 8) = v;
        } else {
            *(u32x4v*)((u16*)outp + (u64)(m0 + rr) * N_ + n0 + nc * 8) = v;
        }
    }
}

// FFN1: grid (32,32) flattened with bijective XCD swizzle
template <int MODE>
__global__ __launch_bounds__(512, 4)
void gemm_kernel(const u16* __restrict__ A, const u16* __restrict__ Bt,
                 const float* __restrict__ bias, void* __restrict__ outp,
                 int N_, int K_) {
    __shared__ u16 ldsA[2][128 * 64];
    __shared__ u16 ldsB[2][128 * 64];
    const int nwg = gridDim.x * gridDim.y;
    const int fid = blockIdx.x + blockIdx.y * gridDim.x;
    const int s = (fid & 7) * (nwg >> 3) + (fid >> 3);
    const int m0 = (s & (gridDim.x - 1)) * 128;
    const int n0 = (s / gridDim.x) * 128;
    f32x4 acc[2][4];
#pragma unroll
    for (int i = 0; i < 2; i++)
#pragma unroll
        for (int j = 0; j < 4; j++) acc[i][j] = (f32x4){0.f, 0.f, 0.f, 0.f};
    gemm_core(A, Bt, K_, ldsA, ldsB, acc, m0, n0);
    gemm_epilogue<MODE>(acc, bias, outp, N_, m0, n0, 1.f, (u16*)ldsA);
}

__global__ __launch_bounds__(512, 4)
void gemm_qkv_kernel(const u16* __restrict__ A,
                     const u16* __restrict__ Wq, const u16* __restrict__ Wk,
                     const u16* __restrict__ Wv,
                     const float* __restrict__ bq, const float* __restrict__ bk,
                     const float* __restrict__ bv,
                     u16* __restrict__ Qo, u16* __restrict__ Ko, u16* __restrict__ Vo) {
    __shared__ u16 ldsA[2][128 * 64];
    __shared__ u16 ldsB[2][128 * 64];
    // grid (32,8,3) = 768 blocks; bijective XCD swizzle on flat id (chunk 96)
    const int fid = blockIdx.x + blockIdx.y * 32 + blockIdx.z * 256;
    const int s = (fid & 7) * 96 + (fid >> 3);
    const int z = s >> 8;
    const int m0 = (s & 31) * 128;
    const int n0 = ((s >> 5) & 7) * 128;
    const u16* Bt = z == 0 ? Wq : z == 1 ? Wk : Wv;
    const float* bias = z == 0 ? bq : z == 1 ? bk : bv;
    f32x4 acc[2][4];
#pragma unroll
    for (int i = 0; i < 2; i++)
#pragma unroll
        for (int j = 0; j < 4; j++) acc[i][j] = (f32x4){0.f, 0.f, 0.f, 0.f};
    gemm_core(A, Bt, 1024, ldsA, ldsB, acc, m0, n0);
    if (z == 2)
        gemm_epilogue<MODE_VT>(acc, bias, Vo, 1024, m0, n0, 1.f, (u16*)ldsA);
    else
        gemm_epilogue<MODE_QK>(acc, bias, z == 0 ? Qo : Ko, 1024, m0, n0,
                               z == 0 ? QSCALE : 1.f, (u16*)ldsA);
}

// ---------- GEMM B: 128x64, 512 threads / 8 waves (16x64), 3-ring vmcnt(3) ----------
template <bool RB16>
__global__ __launch_bounds__(512, 4)
void gemm64_kernel(const u16* __restrict__ A, const u16* __restrict__ Bt,
                   const float* __restrict__ bias, const void* __restrict__ resid,
                   float* __restrict__ outp, int K_) {
    __shared__ u16 ldsA[3][128 * 64];
    __shared__ u16 ldsB[3][64 * 64];
    const int tid = threadIdx.x;
    const int lane = tid & 63;
    const int w = tid >> 6;
    const int l15 = lane & 15, l4 = lane >> 4;
    // grid (32,16) = 512 blocks; bijective XCD swizzle (chunk 64)
    const int fid = blockIdx.x + blockIdx.y * 32;
    const int s = (fid & 7) * 64 + (fid >> 3);
    const int m0 = (s & 31) * 128;
    const int n0 = (s >> 5) * 64;
    const int srow = tid >> 3;
    const int sc = (tid & 7) ^ (srow & 7);

    const u16* ap[2];
    const u16* bp0;
    ap[0] = A + (u64)(m0 + srow) * K_ + sc * 8;
    ap[1] = A + (u64)(m0 + 64 + srow) * K_ + sc * 8;
    bp0 = Bt + (u64)(n0 + srow) * K_ + sc * 8;

    auto stage = [&](int buf) {
#pragma unroll
        for (int i = 0; i < 2; i++) {
            gload16(ap[i], (const char*)ldsA[buf] + (i * 512 + tid) * 16);
            ap[i] += 64;
        }
        gload16(bp0, (const char*)ldsB[buf] + tid * 16);
        bp0 += 64;
    };

    f32x4 acc[4];
#pragma unroll
    for (int j = 0; j < 4; j++) acc[j] = (f32x4){0.f, 0.f, 0.f, 0.f};

    auto compute = [&](const u16* A_, const u16* B_) {
#pragma unroll
        for (int ks = 0; ks < 2; ks++) {
            bf16x8 af, bfr[4];
            {
                int row = w * 16 + l15;
                af = *(const bf16x8*)((const char*)A_ + row * 128 +
                                      (((ks * 4 + l4) ^ (row & 7)) * 16));
            }
#pragma unroll
            for (int ni = 0; ni < 4; ni++) {
                int row = ni * 16 + l15;
                bfr[ni] = *(const bf16x8*)((const char*)B_ + row * 128 +
                                           (((ks * 4 + l4) ^ (row & 7)) * 16));
            }
            __builtin_amdgcn_s_setprio(1);
#pragma unroll
            for (int ni = 0; ni < 4; ni++)
                acc[ni] = __builtin_amdgcn_mfma_f32_16x16x32_bf16(af, bfr[ni], acc[ni], 0, 0, 0);
            __builtin_amdgcn_s_setprio(0);
        }
    };

    const int nk = K_ >> 6;
    stage(0);
    stage(1);
    int cb = 0, sb = 2;
    for (int t = 0; t < nk; t++) {
        if (t < nk - 1) {
            asm volatile("s_waitcnt vmcnt(3)" ::: "memory");
        } else {
            asm volatile("s_waitcnt vmcnt(0)" ::: "memory");
        }
        __builtin_amdgcn_s_barrier();
        if (t + 2 < nk) stage(sb);
        compute(ldsA[cb], ldsB[cb]);
        cb = (cb == 2) ? 0 : cb + 1;
        sb = (sb == 2) ? 0 : sb + 1;
    }

    float* fl = (float*)ldsA;
    __syncthreads();
#pragma unroll
    for (int ni = 0; ni < 4; ni++) {
        const int nl = ni * 16 + l15;
        const int mlb = w * 16 + l4 * 4;
#pragma unroll
        for (int r = 0; r < 4; r++)
            fl[(mlb + r) * 68 + nl] = acc[ni][r];
    }
    __syncthreads();
#pragma unroll
    for (int it = 0; it < 4; it++) {
        int c = it * 512 + tid;
        int rr = c >> 4, nc = c & 15;
        f32x4 v = *(const f32x4*)(fl + rr * 68 + nc * 4);
        const int n = n0 + nc * 4;
        float4 bv = *(const float4*)(bias + n);
        const u64 i2 = (u64)(m0 + rr) * 1024 + n;
        float4 rv;
        if (RB16) {
            uint2 rb = *(const uint2*)((const u16*)resid + i2);
            rv.x = bf2f((u16)(rb.x & 0xffffu)); rv.y = bf2f((u16)(rb.x >> 16));
            rv.z = bf2f((u16)(rb.y & 0xffffu)); rv.w = bf2f((u16)(rb.y >> 16));
        } else {
            rv = *(const float4*)((const float*)resid + i2);
        }
        float4 o;
        o.x = v[0] + bv.x + rv.x;
        o.y = v[1] + bv.y + rv.y;
        o.z = v[2] + bv.z + rv.z;
        o.w = v[3] + bv.w + rv.w;
        *(float4*)(outp + i2) = o;
    }
}

// ---------- flash attention (v11: 3-deep LDS pipeline, counted vmcnt(4)) ----------
__global__ __launch_bounds__(256, 3)
void attn_kernel(const u16* __restrict__ Qg, const u16* __restrict__ Kg,
                 const u16* __restrict__ Vtg, u16* __restrict__ Og) {
    __shared__ u16 ldsK[3][64 * 64];
    __shared__ u16 ldsV[3][64 * 64];
    const int tid = threadIdx.x;
    const int lane = tid & 63;
    const int w = tid >> 6;
    const int l15 = lane & 15, l4 = lane >> 4;
    const int id = blockIdx.x;
    const int swz = (id & 7) * 128 + (id >> 3);
    const int bh = swz >> 5;
    const int qblk = swz & 31;
    const u64 kvbase = (u64)bh * 2048 * 64;
    const int qw0 = qblk * 64 + w * 16;

    const int srow = tid >> 3;
    const int sc8 = ((tid & 7) ^ (srow & 7)) * 8;
    const u16* kq0 = Kg + kvbase + (u64)srow * 64 + sc8;
    const u16* kq1 = Kg + kvbase + (u64)(srow + 32) * 64 + sc8;
    const u16* vq0 = Vtg + kvbase + (u64)srow * 2048 + sc8;
    const u16* vq1 = Vtg + kvbase + (u64)(srow + 32) * 2048 + sc8;

    auto stage = [&](int buf) {
        gload16(kq0, (const char*)ldsK[buf] + tid * 16);
        gload16(kq1, (const char*)ldsK[buf] + (256 + tid) * 16);
        gload16(vq0, (const char*)ldsV[buf] + tid * 16);
        gload16(vq1, (const char*)ldsV[buf] + (256 + tid) * 16);
        kq0 += 4096; kq1 += 4096; vq0 += 64; vq1 += 64;
    };

    bf16x8 aq[2];
#pragma unroll
    for (int ks = 0; ks < 2; ks++)
        aq[ks] = *(const bf16x8*)(Qg + kvbase + (u64)(qw0 + l15) * 64 + ks * 32 + l4 * 8);
    asm volatile("s_waitcnt vmcnt(0)" ::: "memory");

    stage(0);
    stage(1);

    const u32x4v onesw = {0x3F803F80u, 0x3F803F80u, 0x3F803F80u, 0x3F803F80u};
    const bf16x8 aones = __builtin_bit_cast(bf16x8, onesw);

    f32x4 acco[4];
#pragma unroll
    for (int i = 0; i < 4; i++) acco[i] = (f32x4){0.f, 0.f, 0.f, 0.f};
    f32x4 lacc = (f32x4){0.f, 0.f, 0.f, 0.f};

    auto tile_body = [&](const u16* K_, const u16* V_) {
        f32x4 sf[4];
#pragma unroll
        for (int f = 0; f < 4; f++) sf[f] = (f32x4){0.f, 0.f, 0.f, 0.f};
#pragma unroll
        for (int ks = 0; ks < 2; ks++) {
            bf16x8 ak[4];
#pragma unroll
            for (int f = 0; f < 4; f++) {
                int row = f * 16 + l15;
                ak[f] = *(const bf16x8*)((const char*)K_ + row * 128 +
                                         (((ks * 4 + l4) ^ (row & 7)) * 16));
            }
            __builtin_amdgcn_s_setprio(1);
#pragma unroll
            for (int f = 0; f < 4; f++)
                sf[f] = __builtin_amdgcn_mfma_f32_16x16x32_bf16(ak[f], aq[ks], sf[f], 0, 0, 0);
            __builtin_amdgcn_s_setprio(0);
        }

        u32 A[4], B[4];
#pragma unroll
        for (int f = 0; f < 4; f++) {
            float p0 = ex2(sf[f][0]);
            float p1 = ex2(sf[f][1]);
            float p2 = ex2(sf[f][2]);
            float p3 = ex2(sf[f][3]);
            A[f] = pack2bf(p0, p1);
            B[f] = pack2bf(p2, p3);
        }
        asm volatile("v_permlane32_swap_b32 %0, %1" : "+v"(A[0]), "+v"(A[1]));
        asm volatile("v_permlane16_swap_b32 %0, %1" : "+v"(A[0]), "+v"(A[1]));
        asm volatile("v_permlane32_swap_b32 %0, %1" : "+v"(B[0]), "+v"(B[1]));
        asm volatile("v_permlane16_swap_b32 %0, %1" : "+v"(B[0]), "+v"(B[1]));
        asm volatile("v_permlane32_swap_b32 %0, %1" : "+v"(A[2]), "+v"(A[3]));
        asm volatile("v_permlane16_swap_b32 %0, %1" : "+v"(A[2]), "+v"(A[3]));
        asm volatile("v_permlane32_swap_b32 %0, %1" : "+v"(B[2]), "+v"(B[3]));
        asm volatile("v_permlane16_swap_b32 %0, %1" : "+v"(B[2]), "+v"(B[3]));

#pragma unroll
        for (int ks = 0; ks < 2; ks++) {
            u32x4v pw = {A[2 * ks], B[2 * ks], A[2 * ks + 1], B[2 * ks + 1]};
            bf16x8 pfrag = __builtin_bit_cast(bf16x8, pw);
            bf16x8 av[4];
#pragma unroll
            for (int nf = 0; nf < 4; nf++) {
                int row = nf * 16 + l15;
                av[nf] = *(const bf16x8*)((const char*)V_ + row * 128 +
                                          (((ks * 4 + l4) ^ (row & 7)) * 16));
            }
            __builtin_amdgcn_s_setprio(1);
            lacc = __builtin_amdgcn_mfma_f32_16x16x32_bf16(aones, pfrag, lacc, 0, 0, 0);
#pragma unroll
            for (int nf = 0; nf < 4; nf++)
                acco[nf] = __builtin_amdgcn_mfma_f32_16x16x32_bf16(av[nf], pfrag, acco[nf], 0, 0, 0);
            __builtin_amdgcn_s_setprio(0);
        }
    };

    int cb = 0;
    int sb = 2;
    for (int t = 0; t < 31; t++) {
        asm volatile("s_waitcnt vmcnt(4)" ::: "memory");
        __builtin_amdgcn_s_barrier();
        if (t < 30) stage(sb);
        tile_body(ldsK[cb], ldsV[cb]);
        cb = (cb == 2) ? 0 : cb + 1;
        sb = (sb == 2) ? 0 : sb + 1;
    }
    asm volatile("s_waitcnt vmcnt(0)" ::: "memory");
    __builtin_amdgcn_s_barrier();
    tile_body(ldsK[cb], ldsV[cb]);

    const float inv = 1.f / lacc[0];

    const int b = bh >> 4, h = bh & 15;
    const int tq = qw0 + l15;
#pragma unroll
    for (int nf = 0; nf < 4; nf++) {
        const int d = nf * 16 + l4 * 4;
        u32 lo = pack2bf(acco[nf][0] * inv, acco[nf][1] * inv);
        u32 hi = pack2bf(acco[nf][2] * inv, acco[nf][3] * inv);
        *(uint2*)(Og + ((u64)(b * 2048 + tq) << 10) + h * 64 + d) = make_uint2(lo, hi);
    }
}

// ---------- layernorm (WF32: f32 out; WB16: bf16 out) ----------
template <bool WF32, bool WB16>
__global__ __launch_bounds__(256, 4)
void ln_kernel(const float* __restrict__ in, const float* __restrict__ gam,
               const float* __restrict__ bet, float* __restrict__ outf,
               u16* __restrict__ outb) {
    __shared__ float red[2][4];
    const int row = blockIdx.x;
    const int tid = threadIdx.x;
    float4 v = ((const float4*)(in + (u64)row * 1024))[tid];
    float s = v.x + v.y + v.z + v.w;
    float sq = v.x * v.x + v.y * v.y + v.z * v.z + v.w * v.w;
#pragma unroll
    for (int sh = 1; sh < 64; sh <<= 1) {
        s += __shfl_xor(s, sh, 64);
        sq += __shfl_xor(sq, sh, 64);
    }
    if ((tid & 63) == 0) { red[0][tid >> 6] = s; red[1][tid >> 6] = sq; }
    __syncthreads();
    s = red[0][0] + red[0][1] + red[0][2] + red[0][3];
    sq = red[1][0] + red[1][1] + red[1][2] + red[1][3];
    float mu = s * (1.f / 1024.f);
    float var = sq * (1.f / 1024.f) - mu * mu;
    float inv = rsqrtf(var + 1e-5f);
    float4 g = ((const float4*)gam)[tid];
    float4 bb = ((const float4*)bet)[tid];
    float4 o;
    o.x = (v.x - mu) * inv * g.x + bb.x;
    o.y = (v.y - mu) * inv * g.y + bb.y;
    o.z = (v.z - mu) * inv * g.z + bb.z;
    o.w = (v.w - mu) * inv * g.w + bb.w;
    if (WF32) ((float4*)(outf + (u64)row * 1024))[tid] = o;
    if (WB16) {
        ((uint2*)(outb + (u64)row * 1024))[tid] = make_uint2(pack2bf(o.x, o.y), pack2bf(o.z, o.w));
    }
}

// ---------- launcher ----------
extern "C" void kernel_launch(void* const* d_in, const int* in_sizes, int n_in,
                              void* d_out, int out_size, void* d_ws, size_t ws_size,
                              hipStream_t stream) {
    (void)in_sizes; (void)n_in; (void)out_size; (void)ws_size;
    const float* x  = (const float*)d_in[0];
    const float* Wq = (const float*)d_in[1];
    const float* bq = (const float*)d_in[2];
    const float* Wk = (const float*)d_in[3];
    const float* bk = (const float*)d_in[4];
    const float* Wv = (const float*)d_in[5];
    const float* bv = (const float*)d_in[6];
    const float* Wo = (const float*)d_in[7];
    const float* bo = (const float*)d_in[8];
    const float* g1 = (const float*)d_in[9];
    const float* be1 = (const float*)d_in[10];
    const float* g2 = (const float*)d_in[11];
    const float* be2 = (const float*)d_in[12];
    const float* W1 = (const float*)d_in[13];
    const float* b1 = (const float*)d_in[14];
    const float* W2 = (const float*)d_in[15];
    const float* b2 = (const float*)d_in[16];

    char* ws = (char*)d_ws;
    const u64 MB = 1024ull * 1024ull;
    u16* xb    = (u16*)(ws + 0);
    u16* Wqt   = (u16*)(ws + 8 * MB);
    u16* Wkt   = (u16*)(ws + 10 * MB);
    u16* Wvt   = (u16*)(ws + 12 * MB);
    u16* Wot   = (u16*)(ws + 14 * MB);
    u16* W1t   = (u16*)(ws + 16 * MB);
    u16* W2t   = (u16*)(ws + 24 * MB);
    u16* Qb    = (u16*)(ws + 32 * MB);
    u16* Kb    = (u16*)(ws + 40 * MB);
    u16* Vtb   = (u16*)(ws + 48 * MB);
    u16* Ob    = (u16*)(ws + 56 * MB);
    float* pre1 = (float*)(ws + 64 * MB);
    u16* hb    = (u16*)(ws + 96 * MB);
    u16* ffb   = (u16*)(ws + 104 * MB);
    float* pre2 = (float*)(ws + 80 * MB);

    prep_kernel<<<7168, 256, 0, stream>>>(x, xb, Wq, Wk, Wv, Wo,
                                          Wqt, Wkt, Wvt, Wot, W1, W1t, W2, W2t);

    gemm_qkv_kernel<<<dim3(32, 8, 3), 512, 0, stream>>>(xb, Wqt, Wkt, Wvt,
                                                        bq, bk, bv, Qb, Kb, Vtb);

    attn_kernel<<<1024, 256, 0, stream>>>(Qb, Kb, Vtb, Ob);

    gemm64_kernel<false><<<dim3(32, 16), 512, 0, stream>>>(Ob, Wot, bo, x, pre1, 1024);
    ln_kernel<false, true><<<4096, 256, 0, stream>>>(pre1, g1, be1, nullptr, hb);
    gemm_kernel<MODE_RELU><<<dim3(32, 32), 512, 0, stream>>>(hb, W1t, b1, ffb, 4096, 1024);
    gemm64_kernel<true><<<dim3(32, 16), 512, 0, stream>>>(ffb, W2t, b2, hb, pre2, 4096);
    ln_kernel<true, false><<<4096, 256, 0, stream>>>(pre2, g2, be2, (float*)d_out, nullptr);
}

// Round 20
// 202.139 us; speedup vs baseline: 1.1779x; 1.1779x over previous
//
#include <hip/hip_runtime.h>
#include <cstdint>

#define DEVI __device__ __forceinline__

typedef float f32x4 __attribute__((ext_vector_type(4)));
typedef __bf16 bf16x8 __attribute__((ext_vector_type(8)));
typedef unsigned int u32x4v __attribute__((ext_vector_type(4)));
typedef unsigned short u16;
typedef unsigned int u32;
typedef unsigned long long u64;

#define LOG2E 1.44269504088896f
#define QSCALE (0.125f * LOG2E)

// ---------- helpers ----------
DEVI u16 bf16bits(float f) {
    u32 u = __builtin_bit_cast(u32, f);
    u32 r = u + 0x7fffu + ((u >> 16) & 1u);
    return (u16)(r >> 16);
}

DEVI float bf2f(u16 v) {
    u32 u = (u32)v << 16;
    return __builtin_bit_cast(float, u);
}

DEVI u32 pack2bf(float a, float b) {
    u16 x = __builtin_bit_cast(u16, (__bf16)a);
    u16 y = __builtin_bit_cast(u16, (__bf16)b);
    return (u32)x | ((u32)y << 16);
}

DEVI float ex2(float x) {
    float r;
    asm("v_exp_f32 %0, %1" : "=v"(r) : "v"(x));
    return r;
}

DEVI void gload16(const void* g, const void* l) {
    __builtin_amdgcn_global_load_lds(
        (const __attribute__((address_space(1))) void*)(u64)(uintptr_t)g,
        (__attribute__((address_space(3))) void*)(u32)(uintptr_t)l,
        16, 0, 0);
}

// ---------- fused prep ----------
__global__ __launch_bounds__(256)
void prep_kernel(const float* __restrict__ x, u16* __restrict__ xb,
                 const float* __restrict__ Wq, const float* __restrict__ Wk,
                 const float* __restrict__ Wv, const float* __restrict__ Wo,
                 u16* __restrict__ Wqt, u16* __restrict__ Wkt,
                 u16* __restrict__ Wvt, u16* __restrict__ Wot,
                 const float* __restrict__ W1, u16* __restrict__ W1t,
                 const float* __restrict__ W2, u16* __restrict__ W2t) {
    __shared__ float t[64][65];
    const int b = blockIdx.x;
    const int tid = threadIdx.x;
    if (b < 4096) {
        int i = b * 256 + tid;
        float4 v = ((const float4*)x)[i];
        ((uint2*)xb)[i] = make_uint2(pack2bf(v.x, v.y), pack2bf(v.z, v.w));
        return;
    }
    const float* src;
    u16* dst;
    int K_, N_, k0, n0;
    if (b < 5120) {
        int l = b - 4096;
        int z = l >> 8;
        l &= 255;
        src = z == 0 ? Wq : z == 1 ? Wk : z == 2 ? Wv : Wo;
        dst = z == 0 ? Wqt : z == 1 ? Wkt : z == 2 ? Wvt : Wot;
        K_ = 1024; N_ = 1024;
        k0 = (l & 15) * 64; n0 = (l >> 4) * 64;
    } else if (b < 6144) {
        int l = b - 5120;
        src = W1; dst = W1t; K_ = 1024; N_ = 4096;
        k0 = (l & 15) * 64; n0 = (l >> 4) * 64;
    } else {
        int l = b - 6144;
        src = W2; dst = W2t; K_ = 4096; N_ = 1024;
        k0 = (l & 63) * 64; n0 = (l >> 6) * 64;
    }
#pragma unroll
    for (int i = 0; i < 16; i++) {
        int idx = i * 256 + tid;
        int r = idx >> 6, c = idx & 63;
        t[r][c] = src[(u64)(k0 + r) * N_ + n0 + c];
    }
    __syncthreads();
#pragma unroll
    for (int i = 0; i < 16; i++) {
        int idx = i * 256 + tid;
        int r = idx >> 6, c = idx & 63;
        dst[(u64)(n0 + r) * K_ + k0 + c] = bf16bits(t[c][r]);
    }
}

// ---------- GEMM A: 128x128 tile, asymmetric 3A/2B ring, counted vmcnt ----------
enum { MODE_QK = 0, MODE_VT = 1, MODE_RESID = 2, MODE_RELU = 3 };

DEVI void gemm_core(const u16* __restrict__ A, const u16* __restrict__ Bt, int K_,
                    u16 (*ldsA)[128 * 64], u16 (*ldsB)[128 * 64],
                    f32x4 (&acc)[4][4], int m0, int n0) {
    const int tid = threadIdx.x;
    const int lane = tid & 63;
    const int wid = tid >> 6;
    const int wr = wid >> 1, wc = wid & 1;
    const int l15 = lane & 15, l4 = lane >> 4;
    const int srow = tid >> 3;
    const int sc = (tid & 7) ^ (srow & 7);

    const u16* ap[4];
    const u16* bp[4];
#pragma unroll
    for (int i = 0; i < 4; i++) {
        ap[i] = A + (u64)(m0 + i * 32 + srow) * K_ + sc * 8;
        bp[i] = Bt + (u64)(n0 + i * 32 + srow) * K_ + sc * 8;
    }

    auto stageA = [&](int buf) {
#pragma unroll
        for (int i = 0; i < 4; i++) {
            gload16(ap[i], (const char*)ldsA[buf] + (i * 256 + tid) * 16);
            ap[i] += 64;
        }
    };
    auto stageB = [&](int buf) {
#pragma unroll
        for (int i = 0; i < 4; i++) {
            gload16(bp[i], (const char*)ldsB[buf] + (i * 256 + tid) * 16);
            bp[i] += 64;
        }
    };

    auto compute = [&](const u16* A_, const u16* B_) {
#pragma unroll
        for (int ks = 0; ks < 2; ks++) {
            bf16x8 af[4], bfr[4];
#pragma unroll
            for (int mi = 0; mi < 4; mi++) {
                int row = wr * 64 + mi * 16 + l15;
                af[mi] = *(const bf16x8*)((const char*)A_ + row * 128 +
                                          (((ks * 4 + l4) ^ (row & 7)) * 16));
            }
#pragma unroll
            for (int ni = 0; ni < 4; ni++) {
                int row = wc * 64 + ni * 16 + l15;
                bfr[ni] = *(const bf16x8*)((const char*)B_ + row * 128 +
                                           (((ks * 4 + l4) ^ (row & 7)) * 16));
            }
            __builtin_amdgcn_s_setprio(1);
#pragma unroll
            for (int mi = 0; mi < 4; mi++)
#pragma unroll
                for (int ni = 0; ni < 4; ni++)
                    acc[mi][ni] = __builtin_amdgcn_mfma_f32_16x16x32_bf16(
                        af[mi], bfr[ni], acc[mi][ni], 0, 0, 0);
            __builtin_amdgcn_s_setprio(0);
        }
    };

    const int nk = K_ >> 6;
    stageA(0);
    stageB(0);
    stageA(1);
    int ca = 0, cbb = 0, sa = 2, sb = 1;
    for (int t = 0; t < nk; t++) {
        if (t < nk - 1) {
            asm volatile("s_waitcnt vmcnt(4)" ::: "memory");
        } else {
            asm volatile("s_waitcnt vmcnt(0)" ::: "memory");
        }
        __builtin_amdgcn_s_barrier();
        if (t + 1 < nk) { stageB(sb); sb ^= 1; }
        if (t + 2 < nk) { stageA(sa); sa = (sa == 2) ? 0 : sa + 1; }
        compute(ldsA[ca], ldsB[cbb]);
        ca = (ca == 2) ? 0 : ca + 1;
        cbb ^= 1;
    }
}

template <int MODE>
DEVI void gemm_epilogue(f32x4 (&acc)[4][4], const float* __restrict__ bias,
                        const float* __restrict__ resid, void* __restrict__ outp,
                        int N_, int m0, int n0, float scale) {
    const int tid = threadIdx.x;
    const int lane = tid & 63;
    const int wid = tid >> 6;
    const int wr = wid >> 1, wc = wid & 1;
    const int l15 = lane & 15, l4 = lane >> 4;
#pragma unroll
    for (int mi = 0; mi < 4; mi++) {
#pragma unroll
        for (int ni = 0; ni < 4; ni++) {
            const int n = n0 + wc * 64 + ni * 16 + l15;
            const float bv = bias[n];
            const int mb = m0 + wr * 64 + mi * 16 + l4 * 4;
            if (MODE == MODE_VT) {
                const int b = mb >> 11, t = mb & 2047;
                const int hh = n >> 6, d = n & 63;
                u32 lo = pack2bf(acc[mi][ni][0] + bv, acc[mi][ni][1] + bv);
                u32 hi = pack2bf(acc[mi][ni][2] + bv, acc[mi][ni][3] + bv);
                u64 idx = ((u64)((b << 4) + hh) * 64 + d) * 2048 + t;
                *(uint2*)((u16*)outp + idx) = make_uint2(lo, hi);
            } else {
#pragma unroll
                for (int r = 0; r < 4; r++) {
                    const int m = mb + r;
                    const float v = acc[mi][ni][r] + bv;
                    if (MODE == MODE_QK) {
                        const int b = m >> 11, t = m & 2047;
                        const int hh = n >> 6, d = n & 63;
                        ((u16*)outp)[(((u64)((b << 4) + hh) * 2048 + t) << 6) + d] =
                            bf16bits(v * scale);
                    } else if (MODE == MODE_RESID) {
                        const u64 i2 = (u64)m * N_ + n;
                        ((float*)outp)[i2] = v + resid[i2];
                    } else {
                        ((u16*)outp)[(u64)m * N_ + n] = bf16bits(fmaxf(v, 0.f));
                    }
                }
            }
        }
    }
}

template <int MODE>
__global__ __launch_bounds__(256, 2)
void gemm_kernel(const u16* __restrict__ A, const u16* __restrict__ Bt,
                 const float* __restrict__ bias, const float* __restrict__ resid,
                 void* __restrict__ outp, int N_, int K_) {
    __shared__ u16 ldsA[3][128 * 64];
    __shared__ u16 ldsB[2][128 * 64];
    const int m0 = blockIdx.x * 128;
    const int n0 = blockIdx.y * 128;
    f32x4 acc[4][4];
#pragma unroll
    for (int i = 0; i < 4; i++)
#pragma unroll
        for (int j = 0; j < 4; j++) acc[i][j] = (f32x4){0.f, 0.f, 0.f, 0.f};
    gemm_core(A, Bt, K_, ldsA, ldsB, acc, m0, n0);
    gemm_epilogue<MODE>(acc, bias, resid, outp, N_, m0, n0, 1.f);
}

__global__ __launch_bounds__(256, 2)
void gemm_qkv_kernel(const u16* __restrict__ A,
                     const u16* __restrict__ Wq, const u16* __restrict__ Wk,
                     const u16* __restrict__ Wv,
                     const float* __restrict__ bq, const float* __restrict__ bk,
                     const float* __restrict__ bv,
                     u16* __restrict__ Qo, u16* __restrict__ Ko, u16* __restrict__ Vo) {
    __shared__ u16 ldsA[3][128 * 64];
    __shared__ u16 ldsB[2][128 * 64];
    const int z = blockIdx.z;
    const u16* Bt = z == 0 ? Wq : z == 1 ? Wk : Wv;
    const float* bias = z == 0 ? bq : z == 1 ? bk : bv;
    const int m0 = blockIdx.x * 128;
    const int n0 = blockIdx.y * 128;
    f32x4 acc[4][4];
#pragma unroll
    for (int i = 0; i < 4; i++)
#pragma unroll
        for (int j = 0; j < 4; j++) acc[i][j] = (f32x4){0.f, 0.f, 0.f, 0.f};
    gemm_core(A, Bt, 1024, ldsA, ldsB, acc, m0, n0);
    if (z == 2)
        gemm_epilogue<MODE_VT>(acc, bias, nullptr, Vo, 1024, m0, n0, 1.f);
    else
        gemm_epilogue<MODE_QK>(acc, bias, nullptr, z == 0 ? Qo : Ko, 1024, m0, n0,
                               z == 0 ? QSCALE : 1.f);
}

// ---------- GEMM B: 128x64 tile, 3-deep counted vmcnt (Wo / FFN2) ----------
template <bool RB16>
__global__ __launch_bounds__(256, 2)
void gemm64_kernel(const u16* __restrict__ A, const u16* __restrict__ Bt,
                   const float* __restrict__ bias, const void* __restrict__ resid,
                   float* __restrict__ outp, int K_) {
    __shared__ u16 ldsA[3][128 * 64];
    __shared__ u16 ldsB[3][64 * 64];
    const int tid = threadIdx.x;
    const int lane = tid & 63;
    const int wid = tid >> 6;
    const int m0 = blockIdx.x * 128;
    const int n0 = blockIdx.y * 64;
    const int l15 = lane & 15, l4 = lane >> 4;
    const int srow = tid >> 3;
    const int sc = (tid & 7) ^ (srow & 7);

    const u16* ap[4];
    const u16* bp[2];
#pragma unroll
    for (int i = 0; i < 4; i++)
        ap[i] = A + (u64)(m0 + i * 32 + srow) * K_ + sc * 8;
#pragma unroll
    for (int i = 0; i < 2; i++)
        bp[i] = Bt + (u64)(n0 + i * 32 + srow) * K_ + sc * 8;

    auto stage = [&](int buf) {
#pragma unroll
        for (int i = 0; i < 4; i++) {
            gload16(ap[i], (const char*)ldsA[buf] + (i * 256 + tid) * 16);
            ap[i] += 64;
        }
#pragma unroll
        for (int i = 0; i < 2; i++) {
            gload16(bp[i], (const char*)ldsB[buf] + (i * 256 + tid) * 16);
            bp[i] += 64;
        }
    };

    f32x4 acc[2][4];
#pragma unroll
    for (int i = 0; i < 2; i++)
#pragma unroll
        for (int j = 0; j < 4; j++) acc[i][j] = (f32x4){0.f, 0.f, 0.f, 0.f};

    auto compute = [&](const u16* A_, const u16* B_) {
#pragma unroll
        for (int ks = 0; ks < 2; ks++) {
            bf16x8 af[2], bfr[4];
#pragma unroll
            for (int mi = 0; mi < 2; mi++) {
                int row = wid * 32 + mi * 16 + l15;
                af[mi] = *(const bf16x8*)((const char*)A_ + row * 128 +
                                          (((ks * 4 + l4) ^ (row & 7)) * 16));
            }
#pragma unroll
            for (int ni = 0; ni < 4; ni++) {
                int row = ni * 16 + l15;
                bfr[ni] = *(const bf16x8*)((const char*)B_ + row * 128 +
                                           (((ks * 4 + l4) ^ (row & 7)) * 16));
            }
            __builtin_amdgcn_s_setprio(1);
#pragma unroll
            for (int mi = 0; mi < 2; mi++)
#pragma unroll
                for (int ni = 0; ni < 4; ni++)
                    acc[mi][ni] = __builtin_amdgcn_mfma_f32_16x16x32_bf16(
                        af[mi], bfr[ni], acc[mi][ni], 0, 0, 0);
            __builtin_amdgcn_s_setprio(0);
        }
    };

    const int nk = K_ >> 6;
    stage(0);
    stage(1);
    int cb = 0, sb = 2;
    for (int t = 0; t < nk; t++) {
        if (t < nk - 1) {
            asm volatile("s_waitcnt vmcnt(6)" ::: "memory");
        } else {
            asm volatile("s_waitcnt vmcnt(0)" ::: "memory");
        }
        __builtin_amdgcn_s_barrier();
        if (t + 2 < nk) stage(sb);
        compute(ldsA[cb], ldsB[cb]);
        cb = (cb == 2) ? 0 : cb + 1;
        sb = (sb == 2) ? 0 : sb + 1;
    }

#pragma unroll
    for (int mi = 0; mi < 2; mi++) {
#pragma unroll
        for (int ni = 0; ni < 4; ni++) {
            const int n = n0 + ni * 16 + l15;
            const float bv = bias[n];
            const int mb = m0 + wid * 32 + mi * 16 + l4 * 4;
#pragma unroll
            for (int r = 0; r < 4; r++) {
                const u64 i2 = (u64)(mb + r) * 1024 + n;
                const float rv = RB16 ? bf2f(((const u16*)resid)[i2])
                                      : ((const float*)resid)[i2];
                outp[i2] = acc[mi][ni][r] + bv + rv;
            }
        }
    }
}

// ---------- flash attention (v11: 3-deep LDS pipeline, counted vmcnt(4)) ----------
__global__ __launch_bounds__(256, 3)
void attn_kernel(const u16* __restrict__ Qg, const u16* __restrict__ Kg,
                 const u16* __restrict__ Vtg, u16* __restrict__ Og) {
    __shared__ u16 ldsK[3][64 * 64];
    __shared__ u16 ldsV[3][64 * 64];
    const int tid = threadIdx.x;
    const int lane = tid & 63;
    const int w = tid >> 6;
    const int l15 = lane & 15, l4 = lane >> 4;
    const int id = blockIdx.x;
    const int swz = (id & 7) * 128 + (id >> 3);
    const int bh = swz >> 5;
    const int qblk = swz & 31;
    const u64 kvbase = (u64)bh * 2048 * 64;
    const int qw0 = qblk * 64 + w * 16;

    const int srow = tid >> 3;
    const int sc8 = ((tid & 7) ^ (srow & 7)) * 8;
    const u16* kq0 = Kg + kvbase + (u64)srow * 64 + sc8;
    const u16* kq1 = Kg + kvbase + (u64)(srow + 32) * 64 + sc8;
    const u16* vq0 = Vtg + kvbase + (u64)srow * 2048 + sc8;
    const u16* vq1 = Vtg + kvbase + (u64)(srow + 32) * 2048 + sc8;

    auto stage = [&](int buf) {
        gload16(kq0, (const char*)ldsK[buf] + tid * 16);
        gload16(kq1, (const char*)ldsK[buf] + (256 + tid) * 16);
        gload16(vq0, (const char*)ldsV[buf] + tid * 16);
        gload16(vq1, (const char*)ldsV[buf] + (256 + tid) * 16);
        kq0 += 4096; kq1 += 4096; vq0 += 64; vq1 += 64;
    };

    bf16x8 aq[2];
#pragma unroll
    for (int ks = 0; ks < 2; ks++)
        aq[ks] = *(const bf16x8*)(Qg + kvbase + (u64)(qw0 + l15) * 64 + ks * 32 + l4 * 8);
    asm volatile("s_waitcnt vmcnt(0)" ::: "memory");

    stage(0);
    stage(1);

    const u32x4v onesw = {0x3F803F80u, 0x3F803F80u, 0x3F803F80u, 0x3F803F80u};
    const bf16x8 aones = __builtin_bit_cast(bf16x8, onesw);

    f32x4 acco[4];
#pragma unroll
    for (int i = 0; i < 4; i++) acco[i] = (f32x4){0.f, 0.f, 0.f, 0.f};
    f32x4 lacc = (f32x4){0.f, 0.f, 0.f, 0.f};

    auto tile_body = [&](const u16* K_, const u16* V_) {
        f32x4 sf[4];
#pragma unroll
        for (int f = 0; f < 4; f++) sf[f] = (f32x4){0.f, 0.f, 0.f, 0.f};
#pragma unroll
        for (int ks = 0; ks < 2; ks++) {
            bf16x8 ak[4];
#pragma unroll
            for (int f = 0; f < 4; f++) {
                int row = f * 16 + l15;
                ak[f] = *(const bf16x8*)((const char*)K_ + row * 128 +
                                         (((ks * 4 + l4) ^ (row & 7)) * 16));
            }
            __builtin_amdgcn_s_setprio(1);
#pragma unroll
            for (int f = 0; f < 4; f++)
                sf[f] = __builtin_amdgcn_mfma_f32_16x16x32_bf16(ak[f], aq[ks], sf[f], 0, 0, 0);
            __builtin_amdgcn_s_setprio(0);
        }

        u32 A[4], B[4];
#pragma unroll
        for (int f = 0; f < 4; f++) {
            float p0 = ex2(sf[f][0]);
            float p1 = ex2(sf[f][1]);
            float p2 = ex2(sf[f][2]);
            float p3 = ex2(sf[f][3]);
            A[f] = pack2bf(p0, p1);
            B[f] = pack2bf(p2, p3);
        }
        asm volatile("v_permlane32_swap_b32 %0, %1" : "+v"(A[0]), "+v"(A[1]));
        asm volatile("v_permlane16_swap_b32 %0, %1" : "+v"(A[0]), "+v"(A[1]));
        asm volatile("v_permlane32_swap_b32 %0, %1" : "+v"(B[0]), "+v"(B[1]));
        asm volatile("v_permlane16_swap_b32 %0, %1" : "+v"(B[0]), "+v"(B[1]));
        asm volatile("v_permlane32_swap_b32 %0, %1" : "+v"(A[2]), "+v"(A[3]));
        asm volatile("v_permlane16_swap_b32 %0, %1" : "+v"(A[2]), "+v"(A[3]));
        asm volatile("v_permlane32_swap_b32 %0, %1" : "+v"(B[2]), "+v"(B[3]));
        asm volatile("v_permlane16_swap_b32 %0, %1" : "+v"(B[2]), "+v"(B[3]));

#pragma unroll
        for (int ks = 0; ks < 2; ks++) {
            u32x4v pw = {A[2 * ks], B[2 * ks], A[2 * ks + 1], B[2 * ks + 1]};
            bf16x8 pfrag = __builtin_bit_cast(bf16x8, pw);
            bf16x8 av[4];
#pragma unroll
            for (int nf = 0; nf < 4; nf++) {
                int row = nf * 16 + l15;
                av[nf] = *(const bf16x8*)((const char*)V_ + row * 128 +
                                          (((ks * 4 + l4) ^ (row & 7)) * 16));
            }
            __builtin_amdgcn_s_setprio(1);
            lacc = __builtin_amdgcn_mfma_f32_16x16x32_bf16(aones, pfrag, lacc, 0, 0, 0);
#pragma unroll
            for (int nf = 0; nf < 4; nf++)
                acco[nf] = __builtin_amdgcn_mfma_f32_16x16x32_bf16(av[nf], pfrag, acco[nf], 0, 0, 0);
            __builtin_amdgcn_s_setprio(0);
        }
    };

    int cb = 0;
    int sb = 2;
    for (int t = 0; t < 31; t++) {
        asm volatile("s_waitcnt vmcnt(4)" ::: "memory");
        __builtin_amdgcn_s_barrier();
        if (t < 30) stage(sb);
        tile_body(ldsK[cb], ldsV[cb]);
        cb = (cb == 2) ? 0 : cb + 1;
        sb = (sb == 2) ? 0 : sb + 1;
    }
    asm volatile("s_waitcnt vmcnt(0)" ::: "memory");
    __builtin_amdgcn_s_barrier();
    tile_body(ldsK[cb], ldsV[cb]);

    const float inv = 1.f / lacc[0];

    const int b = bh >> 4, h = bh & 15;
    const int tq = qw0 + l15;
#pragma unroll
    for (int nf = 0; nf < 4; nf++) {
        const int d = nf * 16 + l4 * 4;
        u32 lo = pack2bf(acco[nf][0] * inv, acco[nf][1] * inv);
        u32 hi = pack2bf(acco[nf][2] * inv, acco[nf][3] * inv);
        *(uint2*)(Og + ((u64)(b * 2048 + tq) << 10) + h * 64 + d) = make_uint2(lo, hi);
    }
}

// ---------- layernorm (WF32: f32 out; WB16: bf16 out) ----------
template <bool WF32, bool WB16>
__global__ __launch_bounds__(256, 4)
void ln_kernel(const float* __restrict__ in, const float* __restrict__ gam,
               const float* __restrict__ bet, float* __restrict__ outf,
               u16* __restrict__ outb) {
    __shared__ float red[2][4];
    const int row = blockIdx.x;
    const int tid = threadIdx.x;
    float4 v = ((const float4*)(in + (u64)row * 1024))[tid];
    float s = v.x + v.y + v.z + v.w;
    float sq = v.x * v.x + v.y * v.y + v.z * v.z + v.w * v.w;
#pragma unroll
    for (int sh = 1; sh < 64; sh <<= 1) {
        s += __shfl_xor(s, sh, 64);
        sq += __shfl_xor(sq, sh, 64);
    }
    if ((tid & 63) == 0) { red[0][tid >> 6] = s; red[1][tid >> 6] = sq; }
    __syncthreads();
    s = red[0][0] + red[0][1] + red[0][2] + red[0][3];
    sq = red[1][0] + red[1][1] + red[1][2] + red[1][3];
    float mu = s * (1.f / 1024.f);
    float var = sq * (1.f / 1024.f) - mu * mu;
    float inv = rsqrtf(var + 1e-5f);
    float4 g = ((const float4*)gam)[tid];
    float4 bb = ((const float4*)bet)[tid];
    float4 o;
    o.x = (v.x - mu) * inv * g.x + bb.x;
    o.y = (v.y - mu) * inv * g.y + bb.y;
    o.z = (v.z - mu) * inv * g.z + bb.z;
    o.w = (v.w - mu) * inv * g.w + bb.w;
    if (WF32) ((float4*)(outf + (u64)row * 1024))[tid] = o;
    if (WB16) {
        ((uint2*)(outb + (u64)row * 1024))[tid] = make_uint2(pack2bf(o.x, o.y), pack2bf(o.z, o.w));
    }
}

// ---------- launcher ----------
extern "C" void kernel_launch(void* const* d_in, const int* in_sizes, int n_in,
                              void* d_out, int out_size, void* d_ws, size_t ws_size,
                              hipStream_t stream) {
    (void)in_sizes; (void)n_in; (void)out_size; (void)ws_size;
    const float* x  = (const float*)d_in[0];
    const float* Wq = (const float*)d_in[1];
    const float* bq = (const float*)d_in[2];
    const float* Wk = (const float*)d_in[3];
    const float* bk = (const float*)d_in[4];
    const float* Wv = (const float*)d_in[5];
    const float* bv = (const float*)d_in[6];
    const float* Wo = (const float*)d_in[7];
    const float* bo = (const float*)d_in[8];
    const float* g1 = (const float*)d_in[9];
    const float* be1 = (const float*)d_in[10];
    const float* g2 = (const float*)d_in[11];
    const float* be2 = (const float*)d_in[12];
    const float* W1 = (const float*)d_in[13];
    const float* b1 = (const float*)d_in[14];
    const float* W2 = (const float*)d_in[15];
    const float* b2 = (const float*)d_in[16];

    char* ws = (char*)d_ws;
    const u64 MB = 1024ull * 1024ull;
    u16* xb    = (u16*)(ws + 0);
    u16* Wqt   = (u16*)(ws + 8 * MB);
    u16* Wkt   = (u16*)(ws + 10 * MB);
    u16* Wvt   = (u16*)(ws + 12 * MB);
    u16* Wot   = (u16*)(ws + 14 * MB);
    u16* W1t   = (u16*)(ws + 16 * MB);
    u16* W2t   = (u16*)(ws + 24 * MB);
    u16* Qb    = (u16*)(ws + 32 * MB);
    u16* Kb    = (u16*)(ws + 40 * MB);
    u16* Vtb   = (u16*)(ws + 48 * MB);
    u16* Ob    = (u16*)(ws + 56 * MB);
    float* pre1 = (float*)(ws + 64 * MB);
    u16* hb    = (u16*)(ws + 96 * MB);
    u16* ffb   = (u16*)(ws + 104 * MB);
    float* pre2 = (float*)(ws + 80 * MB);

    prep_kernel<<<7168, 256, 0, stream>>>(x, xb, Wq, Wk, Wv, Wo,
                                          Wqt, Wkt, Wvt, Wot, W1, W1t, W2, W2t);

    gemm_qkv_kernel<<<dim3(32, 8, 3), 256, 0, stream>>>(xb, Wqt, Wkt, Wvt,
                                                        bq, bk, bv, Qb, Kb, Vtb);

    attn_kernel<<<1024, 256, 0, stream>>>(Qb, Kb, Vtb, Ob);

    gemm64_kernel<false><<<dim3(32, 16), 256, 0, stream>>>(Ob, Wot, bo, x, pre1, 1024);
    ln_kernel<false, true><<<4096, 256, 0, stream>>>(pre1, g1, be1, nullptr, hb);
    gemm_kernel<MODE_RELU><<<dim3(32, 32), 256, 0, stream>>>(hb, W1t, b1, nullptr, ffb, 4096, 1024);
    gemm64_kernel<true><<<dim3(32, 16), 256, 0, stream>>>(ffb, W2t, b2, hb, pre2, 4096);
    ln_kernel<true, false><<<4096, 256, 0, stream>>>(pre2, g2, be2, (float*)d_out, nullptr);
}